// Round 9
// baseline (485.472 us; speedup 1.0000x reference)
//
#include <hip/hip_runtime.h>

// GCN3 round 9: XCD-slab-partitioned gathers. Gathered tables (xb, xa, t2b)
// stored as 8 column-slabs of 16 cols ([slab][node][16] bf16, 1.6MB/slab);
// agg blocks pick slab = blockIdx&7 so each XCD gathers only from its own
// L2-resident slab. Wave = 8 edges x 8 col-chunks, shfl-reduce over edges.
// GEMMs: direct-A + LDS weights (r7). CSR: bucketed counting sort (r4).

typedef __attribute__((ext_vector_type(8))) short short8;   // 8 bf16 (4 VGPR)
typedef __attribute__((ext_vector_type(4))) float f32x4;    // MFMA C/D

static __device__ __forceinline__ unsigned short f2bf(float f){
  union { float f; unsigned u; } v; v.f = f;
  unsigned r = v.u + 0x7FFF + ((v.u >> 16) & 1);            // RNE
  return (unsigned short)(r >> 16);
}
static __device__ __forceinline__ float2 bf2f2(unsigned u){
  union { unsigned u; float f; } a, b;
  a.u = u << 16; b.u = u & 0xffff0000u;
  return make_float2(a.f, b.f);
}

// ---------------- fused: edge binning + W frag-pack + x->bf16 slabs ----------------
__global__ __launch_bounds__(256) void k_prepbin(
    const int* __restrict__ src, const int* __restrict__ dst,
    int* __restrict__ bcur, unsigned* __restrict__ pairs, int E, int binB,
    const float* __restrict__ W1, const float* __restrict__ W2,
    unsigned short* __restrict__ Wf1, unsigned short* __restrict__ Wf2,
    const float4* __restrict__ x, unsigned* __restrict__ xbs, int nv, int n){
  __shared__ int cl[256];
  int blk = blockIdx.x;
  int tid = threadIdx.x;
  if (blk < binB){
    int e0 = blk * 4096 + tid;
    cl[tid] = 0; __syncthreads();
    #pragma unroll
    for (int i = 0; i < 16; i++){
      int e = e0 + i*256;
      if (e < E) atomicAdd(&cl[dst[e] >> 8], 1);
    }
    __syncthreads();
    int c = cl[tid];
    int g = (c > 0) ? atomicAdd(&bcur[tid], c) : 0;   // reserve contiguous run
    cl[tid] = g;
    __syncthreads();
    #pragma unroll
    for (int i = 0; i < 16; i++){
      int e = e0 + i*256;
      if (e < E){
        int d = dst[e];
        int b = d >> 8;
        int p = atomicAdd(&cl[b], 1);
        pairs[(b << 13) + p] = (unsigned)src[e] | ((unsigned)(d & 255) << 16);
      }
    }
  } else if (blk < binB + 256){
    int t = (blk - binB)*256 + tid;                   // 65536 pack threads
    if (t < 32768){
      // Wf1 [16 nt][4 kt][64 lane][8 j] from W1[128][256]
      int j = t & 7, lane = (t>>3) & 63, kt = (t>>9) & 3, nt = t >> 11;
      int nn = nt*16 + (lane & 15);
      int kk = kt*32 + (lane>>4)*8 + j;
      Wf1[t] = f2bf(W1[kk*256 + nn]);
    } else {
      // Wf2 [2 h][8 kt][4 ntl][64 lane][8 j] from W2[256][128]; nt = h*4+ntl
      int o = t - 32768;
      int j = o & 7, lane = (o>>3) & 63, ntl = (o>>9) & 3, kt = (o>>11) & 7, h = o >> 14;
      int nn = (h*4 + ntl)*16 + (lane & 15);
      int kk = kt*32 + (lane>>4)*8 + j;
      Wf2[o] = f2bf(W2[kk*128 + nn]);
    }
  } else {
    int i = (blk - binB - 256)*256 + tid;             // float4 index into x
    if (i < nv){
      float4 v = x[i];
      int row = i >> 5, c4 = i & 31;                  // 4 cols per float4
      int slab = c4 >> 2;                             // 16 cols per slab
      unsigned lo = (unsigned)f2bf(v.x) | ((unsigned)f2bf(v.y) << 16);
      unsigned hi = (unsigned)f2bf(v.z) | ((unsigned)f2bf(v.w) << 16);
      *(uint2*)&xbs[(size_t)slab*n*8 + row*8 + ((c4 & 3) << 1)] = make_uint2(lo, hi);
    }
  }
}

// one block per bucket: node histogram + scans -> rowptr/cnt/dis + csr scatter
__global__ __launch_bounds__(256) void k_place(
    const int* __restrict__ bcur, const unsigned* __restrict__ pairs,
    unsigned short* __restrict__ csr_src, int* __restrict__ rowptr,
    int* __restrict__ cnt, float* __restrict__ dis, int n, int nb){
  __shared__ int sh[256];
  __shared__ int ncnt[256];
  int t = threadIdx.x;
  int b = blockIdx.x;
  int v = (t < nb) ? bcur[t] : 0;
  sh[t] = v; __syncthreads();
  for (int off = 1; off < 256; off <<= 1){
    int x = (t >= off) ? sh[t-off] : 0;
    __syncthreads(); sh[t] += x; __syncthreads();
  }
  int csr_base = (b == 0) ? 0 : sh[b-1];
  int cnt_b = bcur[b];
  ncnt[t] = 0; __syncthreads();
  const unsigned* P = pairs + ((size_t)b << 13);
  for (int i = t; i < cnt_b; i += 256) atomicAdd(&ncnt[P[i] >> 16], 1);
  __syncthreads();
  int c = ncnt[t];
  sh[t] = c; __syncthreads();
  for (int off = 1; off < 256; off <<= 1){
    int x = (t >= off) ? sh[t-off] : 0;
    __syncthreads(); sh[t] += x; __syncthreads();
  }
  int noff = sh[t] - c;
  int node = (b << 8) + t;
  if (node < n){
    rowptr[node] = csr_base + noff;
    cnt[node] = c;
    dis[node] = rsqrtf((float)(c + 1));           // +1 self loop
  }
  ncnt[t] = noff; __syncthreads();
  for (int i = t; i < cnt_b; i += 256){
    unsigned u = P[i];
    int p = atomicAdd(&ncnt[u >> 16], 1);
    csr_src[csr_base + p] = (unsigned short)(u & 0xffff);
  }
}

// ---------------- aggregation L1 (slab): xbs -> xas, bf16 ----------------
// block: slab g = blockIdx&7, 4 nodes (one per wave). lane = edge(8) x chunk(8).
__global__ void k_aggL1(const unsigned* __restrict__ xbs, unsigned* __restrict__ xas,
                        const int* __restrict__ rowptr, const int* __restrict__ cnt,
                        const unsigned short* __restrict__ csr_src,
                        const float* __restrict__ dis, int n){
  int t = threadIdx.x;
  int g = blockIdx.x & 7;
  int node = (blockIdx.x >> 3)*4 + (t >> 6);
  if (node >= n) return;
  int lane = t & 63, e = lane >> 3, c = lane & 7;
  const unsigned* S = xbs + (size_t)g*n*8;          // slab base (dwords)
  float di = dis[node];
  float2 acc;
  {
    float2 sv = bf2f2(S[(size_t)node*8 + c]);
    float s0 = (e == 0) ? di : 0.0f;
    acc.x = s0*sv.x; acc.y = s0*sv.y;
  }
  int start = rowptr[node], mm = cnt[node];
  int j = 0;
  for (; j + 31 < mm; j += 32){                     // 4 x 8 edges in flight
    int idx[4]; float w[4]; unsigned uv[4];
    #pragma unroll
    for (int q = 0; q < 4; q++) idx[q] = csr_src[start + j + q*8 + e];
    #pragma unroll
    for (int q = 0; q < 4; q++){ w[q] = dis[idx[q]]; uv[q] = S[(size_t)idx[q]*8 + c]; }
    #pragma unroll
    for (int q = 0; q < 4; q++){
      float2 u = bf2f2(uv[q]);
      acc.x = fmaf(w[q], u.x, acc.x); acc.y = fmaf(w[q], u.y, acc.y);
    }
  }
  for (; j < mm; j += 8){
    int jj = j + e;
    int idx = csr_src[start + ((jj < mm) ? jj : (mm-1))];
    float w = (jj < mm) ? dis[idx] : 0.0f;
    float2 u = bf2f2(S[(size_t)idx*8 + c]);
    acc.x = fmaf(w, u.x, acc.x); acc.y = fmaf(w, u.y, acc.y);
  }
  #pragma unroll
  for (int off = 8; off < 64; off <<= 1){           // reduce over e
    acc.x += __shfl_down(acc.x, off);
    acc.y += __shfl_down(acc.y, off);
  }
  if (e == 0){
    acc.x *= di; acc.y *= di;
    xas[(size_t)g*n*8 + (size_t)node*8 + c] =
        (unsigned)f2bf(acc.x) | ((unsigned)f2bf(acc.y) << 16);
  }
}

// ---------------- aggregation L2 (slab): t2bs -> h2 fp32 (+b2,relu), u += dot(W3) ----------------
__global__ void k_aggL2(const unsigned* __restrict__ t2bs, float* __restrict__ h2,
                        const int* __restrict__ rowptr, const int* __restrict__ cnt,
                        const unsigned short* __restrict__ csr_src,
                        const float* __restrict__ dis,
                        const float* __restrict__ b2, const float* __restrict__ W3,
                        float* __restrict__ u, int n){
  int t = threadIdx.x;
  int g = blockIdx.x & 7;
  int node = (blockIdx.x >> 3)*4 + (t >> 6);
  if (node >= n) return;
  int lane = t & 63, e = lane >> 3, c = lane & 7;
  const unsigned* S = t2bs + (size_t)g*n*8;
  float di = dis[node];
  float2 acc;
  {
    float2 sv = bf2f2(S[(size_t)node*8 + c]);
    float s0 = (e == 0) ? di : 0.0f;
    acc.x = s0*sv.x; acc.y = s0*sv.y;
  }
  int start = rowptr[node], mm = cnt[node];
  int j = 0;
  for (; j + 31 < mm; j += 32){
    int idx[4]; float w[4]; unsigned uv[4];
    #pragma unroll
    for (int q = 0; q < 4; q++) idx[q] = csr_src[start + j + q*8 + e];
    #pragma unroll
    for (int q = 0; q < 4; q++){ w[q] = dis[idx[q]]; uv[q] = S[(size_t)idx[q]*8 + c]; }
    #pragma unroll
    for (int q = 0; q < 4; q++){
      float2 uu = bf2f2(uv[q]);
      acc.x = fmaf(w[q], uu.x, acc.x); acc.y = fmaf(w[q], uu.y, acc.y);
    }
  }
  for (; j < mm; j += 8){
    int jj = j + e;
    int idx = csr_src[start + ((jj < mm) ? jj : (mm-1))];
    float w = (jj < mm) ? dis[idx] : 0.0f;
    float2 uu = bf2f2(S[(size_t)idx*8 + c]);
    acc.x = fmaf(w, uu.x, acc.x); acc.y = fmaf(w, uu.y, acc.y);
  }
  #pragma unroll
  for (int off = 8; off < 64; off <<= 1){
    acc.x += __shfl_down(acc.x, off);
    acc.y += __shfl_down(acc.y, off);
  }
  if (e == 0){                                      // lanes 0..7 hold 16 cols
    int col = g*16 + c*2;
    float2 b = *(const float2*)&b2[col];
    acc.x = fmaxf(fmaf(di, acc.x, b.x), 0.0f);
    acc.y = fmaxf(fmaf(di, acc.y, b.y), 0.0f);
    *(float2*)&h2[(size_t)node*128 + col] = acc;
    float up = fmaf(acc.x, W3[col], acc.y * W3[col+1]);
    up += __shfl_down(up, 1);                       // reduce over c within 0..7
    up += __shfl_down(up, 2);
    up += __shfl_down(up, 4);
    if (c == 0) atomicAdd(&u[node], up);
  }
}

// ---------------- GEMM1: xa slabs bf16 @ W1 -> h1 fp32 (+b1,relu) + h1b bf16 ----------------
__global__ __launch_bounds__(256) void k_gemm1_mfma(
    const unsigned short* __restrict__ Xas, const unsigned short* __restrict__ Wf1,
    const float* __restrict__ bias, float* __restrict__ out,
    unsigned short* __restrict__ h1b, int n)
{
  __shared__ unsigned short Wl[8*4*64*8];   // 32 KB
  int t = threadIdx.x;
  int row0 = (blockIdx.x >> 1) * 64;
  int h = blockIdx.x & 1;
  int w = t >> 6, lane = t & 63, m = lane & 15, q = lane >> 4;
  int rbase = w*16;
  int rowm = row0 + rbase + m;
  int ra = (rowm < n) ? rowm : (n-1);       // clamp; bad rows discarded at store
  size_t sstr = (size_t)n*16;               // u16 per slab
  short8 af[4];
  #pragma unroll
  for (int kt = 0; kt < 4; kt++){           // cols kt*32+q*8: slab 2kt+(q>>1)
    int slab = 2*kt + (q >> 1);
    af[kt] = *(const short8*)&Xas[(size_t)slab*sstr + (size_t)ra*16 + (q & 1)*8];
  }
  {
    const float4* src = (const float4*)Wf1 + (size_t)h*2048;
    float4* dst = (float4*)Wl;
    #pragma unroll
    for (int i = 0; i < 8; i++) dst[i*256 + t] = src[i*256 + t];
  }
  __syncthreads();
  f32x4 acc[8];
  #pragma unroll
  for (int i = 0; i < 8; i++) acc[i] = (f32x4){0.f,0.f,0.f,0.f};
  const short8* Wv = (const short8*)Wl;
  #pragma unroll
  for (int nt = 0; nt < 8; nt++){
    #pragma unroll
    for (int kt = 0; kt < 4; kt++){
      short8 bfr = Wv[(nt*4 + kt)*64 + lane];
      acc[nt] = __builtin_amdgcn_mfma_f32_16x16x32_bf16(af[kt], bfr, acc[nt], 0, 0, 0);
    }
  }
  int rowa = row0 + rbase + q*4;
  int colb = h*128 + m;
  #pragma unroll
  for (int nt = 0; nt < 8; nt++){
    float b = bias[colb + nt*16];
    #pragma unroll
    for (int r = 0; r < 4; r++){
      int rr = rowa + r;
      if (rr < n){
        float o = fmaxf(acc[nt][r] + b, 0.0f);
        out[(size_t)rr*256 + colb + nt*16] = o;
        h1b[(size_t)rr*256 + colb + nt*16] = f2bf(o);
      }
    }
  }
}

// ---------------- GEMM2: h1b bf16 @ W2 -> t2b slabs; 64 rows x 64-col half ----------------
__global__ __launch_bounds__(256) void k_gemm2_mfma(
    const unsigned short* __restrict__ H1b, const unsigned short* __restrict__ Wf2,
    unsigned short* __restrict__ T2s, int n)
{
  __shared__ unsigned short Wl[32*64*8];    // 32 KB: 8 kt x 4 ntl frags
  int t = threadIdx.x;
  int row0 = (blockIdx.x >> 1) * 64;
  int h = blockIdx.x & 1;
  int w = t >> 6, lane = t & 63, m = lane & 15, q = lane >> 4;
  int rbase = w*16;
  int rowm = row0 + rbase + m;
  int ra = (rowm < n) ? rowm : (n-1);
  const short8* Arow = (const short8*)(H1b + (size_t)ra*256);
  short8 af[8];
  #pragma unroll
  for (int kt = 0; kt < 8; kt++) af[kt] = Arow[kt*4 + q];
  {
    const float4* src = (const float4*)Wf2 + (size_t)h*2048;
    float4* dst = (float4*)Wl;
    #pragma unroll
    for (int i = 0; i < 8; i++) dst[i*256 + t] = src[i*256 + t];
  }
  __syncthreads();
  f32x4 acc[4];
  #pragma unroll
  for (int i = 0; i < 4; i++) acc[i] = (f32x4){0.f,0.f,0.f,0.f};
  const short8* Wv = (const short8*)Wl;
  #pragma unroll
  for (int nt = 0; nt < 4; nt++){
    #pragma unroll
    for (int kt = 0; kt < 8; kt++){
      short8 bfr = Wv[(kt*4 + nt)*64 + lane];
      acc[nt] = __builtin_amdgcn_mfma_f32_16x16x32_bf16(af[kt], bfr, acc[nt], 0, 0, 0);
    }
  }
  size_t sstr = (size_t)n*16;
  int rowa = row0 + rbase + q*4;
  #pragma unroll
  for (int nt = 0; nt < 4; nt++){
    int slab = h*4 + nt;                    // col = h*64+nt*16+m -> slab, in-slab m
    #pragma unroll
    for (int r = 0; r < 4; r++){
      int rr = rowa + r;
      if (rr < n) T2s[(size_t)slab*sstr + (size_t)rr*16 + m] = f2bf(acc[nt][r]);
    }
  }
}

// ---------------- final scalar aggregation ----------------
__global__ void k_agg1d(const float* __restrict__ u, float* __restrict__ y,
                        const int* __restrict__ rowptr, const int* __restrict__ cnt,
                        const unsigned short* __restrict__ csr_src,
                        const float* __restrict__ dis,
                        const float* __restrict__ b3, int n){
  int i = blockIdx.x*256 + threadIdx.x;
  if (i >= n) return;
  float di = dis[i];
  float acc = di * u[i];
  int s0 = rowptr[i], m = cnt[i];
  for (int j = 0; j < m; j++){
    int s = csr_src[s0+j];
    acc = fmaf(dis[s], u[s], acc);
  }
  y[i] = fmaf(di, acc, b3[0]);
}

extern "C" void kernel_launch(void* const* d_in, const int* in_sizes, int n_in,
                              void* d_out, int out_size, void* d_ws, size_t ws_size,
                              hipStream_t stream){
  const float* x  = (const float*)d_in[0];
  const int*  ei  = (const int*)d_in[1];
  const float* W1 = (const float*)d_in[2];
  const float* b1 = (const float*)d_in[3];
  const float* W2 = (const float*)d_in[4];
  const float* b2 = (const float*)d_in[5];
  const float* W3 = (const float*)d_in[6];
  const float* b3 = (const float*)d_in[7];
  const int N = in_sizes[0] / 128;
  const int E = in_sizes[1] / 2;
  const int* src = ei;
  const int* dst = ei + E;
  const int NB = (N + 255) >> 8;      // 196 buckets

  char* p = (char*)d_ws;
  auto alloc = [&](size_t bytes)->char*{
    char* r = p; p += (bytes + 255) & ~(size_t)255; return r;
  };
  int*   bcur    = (int*)  alloc(256*4);                // zeroed together with u
  float* u       = (float*)alloc((size_t)N*4);
  int*   rowptr  = (int*)  alloc((size_t)N*4);
  int*   cnt     = (int*)  alloc((size_t)N*4);
  float* dis     = (float*)alloc((size_t)N*4);
  unsigned* pairs = (unsigned*)alloc((size_t)NB*8192*4);
  unsigned short* csr_src = (unsigned short*)alloc((size_t)E*2);
  unsigned* xbs  = (unsigned*)alloc((size_t)N*128*2);   // bf16 x, 8 slabs
  unsigned* xas  = (unsigned*)alloc((size_t)N*128*2);   // bf16 agg(x), 8 slabs
  unsigned short* h1b = (unsigned short*)alloc((size_t)N*256*2); // bf16 h1 rows
  unsigned short* t2s = (unsigned short*)alloc((size_t)N*128*2); // bf16 t2, 8 slabs
  unsigned short* wf1 = (unsigned short*)alloc(32768*2);
  unsigned short* wf2 = (unsigned short*)alloc(32768*2);

  float* y  = (float*)d_out;
  float* h1 = y + N;
  float* h2 = h1 + (size_t)N*256;

  int bb = (E + 4095)/4096;           // 196 bin blocks
  int nb = (N + 255)/256;
  int xv = N*32;                      // float4 count of x
  int xblk = (xv + 255)/256;

  hipMemsetAsync(bcur, 0, 256*4 + (size_t)N*4, stream);   // bcur + u (adjacent)
  k_prepbin <<<bb + 256 + xblk, 256, 0, stream>>>(
      src, dst, bcur, pairs, E, bb, W1, W2, wf1, wf2,
      (const float4*)x, xbs, xv, N);
  k_place   <<<NB, 256, 0, stream>>>(bcur, pairs, csr_src, rowptr, cnt, dis, N, NB);

  int ab8 = ((N + 3)/4) * 8;          // 4 nodes/block x 8 slabs
  int rb = (N + 63)/64;
  k_aggL1     <<<ab8,  256, 0, stream>>>(xbs, xas, rowptr, cnt, csr_src, dis, N);
  k_gemm1_mfma<<<rb*2, 256, 0, stream>>>((const unsigned short*)xas, wf1, b1, h1, h1b, N);
  k_gemm2_mfma<<<rb*2, 256, 0, stream>>>(h1b, wf2, t2s, N);
  k_aggL2     <<<ab8,  256, 0, stream>>>((const unsigned*)t2s, h2, rowptr, cnt, csr_src, dis, b2, W3, u, N);
  k_agg1d     <<<nb,   256, 0, stream>>>(u, y, rowptr, cnt, csr_src, dis, b3, N);
}